// Round 3
// baseline (270.743 us; speedup 1.0000x reference)
//
#include <hip/hip_runtime.h>
#include <cstdint>
#include <cstddef>

// RNNT joiner: logits[b,t,u,v] = sum_j tanh(E[b,t,j]+P[b,u,j]) * out_w[v,j] + out_b[v]
// B=4 T=256 U=64 D=512 J=640 V=1024.  M = 65536 rows (b,t,u), N=1024, K=640.
//
// ws layout:
//   E  : float [1024][640]            @ 0         (2,621,440 B)
//   P  : float [ 256][640]            @ 2,621,440 (  655,360 B)
//   Wb : bf16 blocked [4][10][16384]  @ 3,276,800 (1,310,720 B)  pre-swizzled 256x64 blocks

typedef __attribute__((ext_vector_type(8))) __bf16 bf16x8;
typedef __attribute__((ext_vector_type(4))) float f32x4;

// XOR swizzle within a [row][64] bf16 tile (row stride 128B).
__device__ __forceinline__ int swz(int row, int kElem) {
  return (row << 6) + (kElem ^ ((row & 7) << 3));
}

__device__ __forceinline__ float fast_tanh(float x) {
  float e = __builtin_amdgcn_exp2f(x * 2.88539008177793f);  // e^(2x)
  return 1.0f - 2.0f * __builtin_amdgcn_rcpf(e + 1.0f);
}

__device__ __forceinline__ void gload_lds16(const void* g, void* l) {
  __builtin_amdgcn_global_load_lds(
      (const __attribute__((address_space(1))) void*)g,
      (__attribute__((address_space(3))) void*)l, 16, 0, 0);
}

// ---------------------------------------------------------------------------
// proj tile: C[mt*128..][nt*128..] = A[128][512] . W[128][512]^T + bias
// 256 threads, tile 128x128, BK=64, N=640 K=512 fixed.
// ---------------------------------------------------------------------------
__device__ void proj_tile(const float* __restrict__ A, const float* __restrict__ W,
                          const float* __restrict__ bias, float* __restrict__ C,
                          int mt, int nt, __bf16* As, __bf16* Bs)
{
  const int tid  = threadIdx.x;
  const int r = tid & 127, half = tid >> 7;
  const int lane = tid & 63, wv = tid >> 6;
  const int wm = wv >> 1, wn = wv & 1;

  const float* arow = A + (size_t)(mt * 128 + r) * 512 + half * 32;
  const float* wrow = W + (size_t)(nt * 128 + r) * 512 + half * 32;

  f32x4 acc[4][4] = {};

  for (int k0 = 0; k0 < 512; k0 += 64) {
#pragma unroll
    for (int s = 0; s < 4; ++s) {
      f32x4 a0 = *(const f32x4*)(arow + k0 + s * 8);
      f32x4 a1 = *(const f32x4*)(arow + k0 + s * 8 + 4);
      f32x4 w0 = *(const f32x4*)(wrow + k0 + s * 8);
      f32x4 w1 = *(const f32x4*)(wrow + k0 + s * 8 + 4);
      bf16x8 za, zw;
#pragma unroll
      for (int j = 0; j < 4; ++j) {
        za[j] = (__bf16)a0[j]; za[4 + j] = (__bf16)a1[j];
        zw[j] = (__bf16)w0[j]; zw[4 + j] = (__bf16)w1[j];
      }
      const int kk = half * 32 + s * 8;
      *(bf16x8*)&As[swz(r, kk)] = za;
      *(bf16x8*)&Bs[swz(r, kk)] = zw;
    }
    __syncthreads();
#pragma unroll
    for (int kk = 0; kk < 2; ++kk) {
      bf16x8 af[4], bfr[4];
#pragma unroll
      for (int i = 0; i < 4; ++i) {
        af[i]  = *(const bf16x8*)&As[swz(wm * 64 + i * 16 + (lane & 15), kk * 32 + (lane >> 4) * 8)];
        bfr[i] = *(const bf16x8*)&Bs[swz(wn * 64 + i * 16 + (lane & 15), kk * 32 + (lane >> 4) * 8)];
      }
#pragma unroll
      for (int mi = 0; mi < 4; ++mi)
#pragma unroll
        for (int ni = 0; ni < 4; ++ni)
          acc[mi][ni] = __builtin_amdgcn_mfma_f32_16x16x32_bf16(af[mi], bfr[ni], acc[mi][ni], 0, 0, 0);
    }
    __syncthreads();
  }

  const int rowbase = mt * 128 + wm * 64;
  const int colbase = nt * 128 + wn * 64;
#pragma unroll
  for (int ni = 0; ni < 4; ++ni) {
    const int col = colbase + ni * 16 + (lane & 15);
    const float bb = bias[col];
#pragma unroll
    for (int mi = 0; mi < 4; ++mi) {
      const int row = rowbase + mi * 16 + (lane >> 4) * 4;
#pragma unroll
      for (int rg = 0; rg < 4; ++rg)
        C[(size_t)(row + rg) * 640 + col] = acc[mi][ni][rg] + bb;
    }
  }
}

// ---------------------------------------------------------------------------
// prep: blocks 0..39 enc-proj, 40..49 pred-proj, 50..369 out_w conversion.
// out_w fp32 [1024][640] -> bf16 blocked [nb(4)][kb(10)][16384], pre-swizzled.
// ---------------------------------------------------------------------------
__global__ __launch_bounds__(256) void prep_kernel(
    const float* __restrict__ enc,  const float* __restrict__ enc_w,  const float* __restrict__ enc_b,
    const float* __restrict__ pred, const float* __restrict__ pred_w, const float* __restrict__ pred_b,
    const float* __restrict__ out_w,
    float* __restrict__ E, float* __restrict__ P, __bf16* __restrict__ Wb)
{
  __shared__ __align__(16) __bf16 As[128 * 64];
  __shared__ __align__(16) __bf16 Bs[128 * 64];
  const int bid = blockIdx.x;
  if (bid < 40) {
    proj_tile(enc, enc_w, enc_b, E, bid / 5, bid % 5, As, Bs);
  } else if (bid < 50) {
    proj_tile(pred, pred_w, pred_b, P, (bid - 40) / 5, (bid - 40) % 5, As, Bs);
  } else {
    const int gid = (bid - 50) * 256 + threadIdx.x;  // 81920 total (1024*80)
    const int v  = gid / 80;
    const int j8 = gid % 80;
    f32x4 w0 = *(const f32x4*)(out_w + (size_t)v * 640 + j8 * 8);
    f32x4 w1 = *(const f32x4*)(out_w + (size_t)v * 640 + j8 * 8 + 4);
    bf16x8 z;
#pragma unroll
    for (int j = 0; j < 4; ++j) { z[j] = (__bf16)w0[j]; z[4 + j] = (__bf16)w1[j]; }
    const int nb = v >> 8, rr = v & 255;
    const int kb = j8 >> 3, kk = (j8 & 7) * 8;
    *(bf16x8*)(Wb + ((size_t)(nb * 10 + kb) << 14) + swz(rr, kk)) = z;
  }
}

// ---------------------------------------------------------------------------
// main: fused tanh(E+P) x Wb GEMM, 2-phase double-buffered pipeline.
// grid = 512*4; block tile 128(M) x 256(N), BK=64, 512 threads = 8 waves (2Mx4N),
// each wave 64x64 via 4x4 frags of mfma_f32_16x16x32_bf16.
// Per K-tile: issue gload_lds(B[t+1]) + global->reg loads(E/P for A[t+1]),
// MFMA on tile t (setprio-wrapped), tanh+ds_write A[t+1], one barrier.
// ---------------------------------------------------------------------------
__global__ __launch_bounds__(512, 2) void joiner_main(
    const float* __restrict__ E, const float* __restrict__ P,
    const __bf16* __restrict__ Wb, const float* __restrict__ outb,
    float* __restrict__ out)
{
  __shared__ __align__(16) __bf16 As[2 * 128 * 64];   // 32 KB (double-buffered)
  __shared__ __align__(16) __bf16 Bs[2 * 256 * 64];   // 64 KB (double-buffered)
  const int tid = threadIdx.x;
  const int nt = blockIdx.x & 3;
  const int mt = blockIdx.x >> 2;
  const int row0 = mt << 7;
  const int b  = row0 >> 14;
  const int t0 = (row0 >> 6) & 255;
  const int r = tid & 127, q = tid >> 7;          // A staging: row r, k-groups q*8 / 32+q*8
  const int lane = tid & 63, wv = tid >> 6;
  const int wm = wv >> 2, wn = wv & 3;            // 2 x 4 wave grid

  const float* ep = E + (size_t)((b << 8) + t0 + (r >> 6)) * 640;
  const float* pp = P + (size_t)((b << 6) + (r & 63)) * 640;
  const __bf16* wsrc = Wb + ((size_t)(nt * 10) << 14);

  f32x4 acc[4][4] = {};
  f32x4 eA[2], eB[2], pA[2], pB[2];               // prefetched A-inputs (next tile)

  auto loadEP = [&](int k0) {
#pragma unroll
    for (int g = 0; g < 2; ++g) {
      const int kk = k0 + g * 32 + q * 8;
      eA[g] = *(const f32x4*)(ep + kk);
      eB[g] = *(const f32x4*)(ep + kk + 4);
      pA[g] = *(const f32x4*)(pp + kk);
      pB[g] = *(const f32x4*)(pp + kk + 4);
    }
  };
  auto writeA = [&](__bf16* Asb) {
#pragma unroll
    for (int g = 0; g < 2; ++g) {
      bf16x8 z;
#pragma unroll
      for (int j = 0; j < 4; ++j) {
        z[j]     = (__bf16)fast_tanh(eA[g][j] + pA[g][j]);
        z[4 + j] = (__bf16)fast_tanh(eB[g][j] + pB[g][j]);
      }
      *(bf16x8*)&Asb[swz(r, g * 32 + q * 8)] = z;
    }
  };
  auto stageB = [&](int kt, __bf16* Bsb) {
#pragma unroll
    for (int c = 0; c < 4; ++c) {
      const int off = c * 4096 + wv * 512;
      gload_lds16(wsrc + (kt << 14) + off + lane * 8, &Bsb[off]);
    }
  };
  auto compute = [&](const __bf16* Asb, const __bf16* Bsb) {
#pragma unroll
    for (int kk = 0; kk < 2; ++kk) {
      bf16x8 af[4], bfr[4];
#pragma unroll
      for (int i = 0; i < 4; ++i) {
        af[i]  = *(const bf16x8*)&Asb[swz(wm * 64 + i * 16 + (lane & 15), kk * 32 + (lane >> 4) * 8)];
        bfr[i] = *(const bf16x8*)&Bsb[swz(wn * 64 + i * 16 + (lane & 15), kk * 32 + (lane >> 4) * 8)];
      }
      __builtin_amdgcn_s_setprio(1);
#pragma unroll
      for (int mi = 0; mi < 4; ++mi)
#pragma unroll
        for (int ni = 0; ni < 4; ++ni)
          acc[mi][ni] = __builtin_amdgcn_mfma_f32_16x16x32_bf16(af[mi], bfr[ni], acc[mi][ni], 0, 0, 0);
      __builtin_amdgcn_s_setprio(0);
    }
  };

  // ---- prologue: tile 0 into buffer 0 ----
  loadEP(0);
  stageB(0, Bs);
  writeA(As);
  __syncthreads();

  // ---- pipelined main loop: tiles 0..8 compute, 1..9 prefetch ----
  int cur = 0;
  for (int kt = 0; kt < 9; ++kt) {
    __bf16* Asn = As + (cur ^ 1) * 8192;
    __bf16* Bsn = Bs + (cur ^ 1) * 16384;
    stageB(kt + 1, Bsn);                 // B[t+1] -> LDS (async, drains at barrier)
    loadEP((kt + 1) << 6);               // E/P[t+1] -> regs (latency hides under MFMA)
    compute(As + cur * 8192, Bs + cur * 16384);
    writeA(Asn);                         // tanh + swizzled ds_write of A[t+1]
    __syncthreads();
    cur ^= 1;
  }
  // ---- epilogue: tile 9 ----
  compute(As + cur * 8192, Bs + cur * 16384);

  const int rowbase = row0 + wm * 64;
  const int colbase = (nt << 8) + wn * 64;
#pragma unroll
  for (int ni = 0; ni < 4; ++ni) {
    const int col = colbase + ni * 16 + (lane & 15);
    const float bb = outb[col];
#pragma unroll
    for (int mi = 0; mi < 4; ++mi) {
      const int row = rowbase + mi * 16 + (lane >> 4) * 4;
#pragma unroll
      for (int rg = 0; rg < 4; ++rg)
        out[(size_t)(row + rg) * 1024 + col] = acc[mi][ni][rg] + bb;
    }
  }
}

extern "C" void kernel_launch(void* const* d_in, const int* in_sizes, int n_in,
                              void* d_out, int out_size, void* d_ws, size_t ws_size,
                              hipStream_t stream) {
  const float* enc    = (const float*)d_in[0];
  const float* pred   = (const float*)d_in[1];
  const float* enc_w  = (const float*)d_in[2];
  const float* enc_b  = (const float*)d_in[3];
  const float* pred_w = (const float*)d_in[4];
  const float* pred_b = (const float*)d_in[5];
  const float* out_w  = (const float*)d_in[6];
  const float* out_b  = (const float*)d_in[7];
  float* out = (float*)d_out;

  char* ws = (char*)d_ws;
  float*  E  = (float*)(ws);                  // 1024*640 f32
  float*  P  = (float*)(ws + 2621440);        //  256*640 f32
  __bf16* Wb = (__bf16*)(ws + 3276800);       // 4*10*16384 bf16, pre-swizzled

  prep_kernel<<<dim3(370), dim3(256), 0, stream>>>(
      enc, enc_w, enc_b, pred, pred_w, pred_b, out_w, E, P, Wb);
  joiner_main<<<dim3(512 * 4), dim3(512), 0, stream>>>(E, P, Wb, out_b, out);
}

// Round 4
// 234.530 us; speedup vs baseline: 1.1544x; 1.1544x over previous
//
#include <hip/hip_runtime.h>
#include <cstdint>
#include <cstddef>

// RNNT joiner: logits[b,t,u,v] = sum_j tanh(E[b,t,j]+P[b,u,j]) * out_w[v,j] + out_b[v]
// B=4 T=256 U=64 D=512 J=640 V=1024.  M = 65536 rows (b,t,u), N=1024, K=640.
//
// ws layout:
//   E  : float [1024][640]            @ 0         (2,621,440 B)
//   P  : float [ 256][640]            @ 2,621,440 (  655,360 B)
//   Wb : bf16 blocked [4][10][16384]  @ 3,276,800 (1,310,720 B)  pre-swizzled 256x64 blocks

typedef __attribute__((ext_vector_type(8))) __bf16 bf16x8;
typedef __attribute__((ext_vector_type(4))) float f32x4;

// XOR swizzle within a [row][64] bf16 tile (row stride 128B).
__device__ __forceinline__ int swz(int row, int kElem) {
  return (row << 6) + (kElem ^ ((row & 7) << 3));
}

__device__ __forceinline__ float fast_tanh(float x) {
  float e = __builtin_amdgcn_exp2f(x * 2.88539008177793f);  // e^(2x)
  return 1.0f - 2.0f * __builtin_amdgcn_rcpf(e + 1.0f);
}

__device__ __forceinline__ void gload_lds16(const void* g, void* l) {
  __builtin_amdgcn_global_load_lds(
      (const __attribute__((address_space(1))) void*)g,
      (__attribute__((address_space(3))) void*)l, 16, 0, 0);
}

// ---------------------------------------------------------------------------
// proj tile: C[mt*128..][nt*128..] = A[128][512] . W[128][512]^T + bias
// ---------------------------------------------------------------------------
__device__ void proj_tile(const float* __restrict__ A, const float* __restrict__ W,
                          const float* __restrict__ bias, float* __restrict__ C,
                          int mt, int nt, __bf16* As, __bf16* Bs)
{
  const int tid  = threadIdx.x;
  const int r = tid & 127, half = tid >> 7;
  const int lane = tid & 63, wv = tid >> 6;
  const int wm = wv >> 1, wn = wv & 1;

  const float* arow = A + (size_t)(mt * 128 + r) * 512 + half * 32;
  const float* wrow = W + (size_t)(nt * 128 + r) * 512 + half * 32;

  f32x4 acc[4][4] = {};

  for (int k0 = 0; k0 < 512; k0 += 64) {
#pragma unroll
    for (int s = 0; s < 4; ++s) {
      f32x4 a0 = *(const f32x4*)(arow + k0 + s * 8);
      f32x4 a1 = *(const f32x4*)(arow + k0 + s * 8 + 4);
      f32x4 w0 = *(const f32x4*)(wrow + k0 + s * 8);
      f32x4 w1 = *(const f32x4*)(wrow + k0 + s * 8 + 4);
      bf16x8 za, zw;
#pragma unroll
      for (int j = 0; j < 4; ++j) {
        za[j] = (__bf16)a0[j]; za[4 + j] = (__bf16)a1[j];
        zw[j] = (__bf16)w0[j]; zw[4 + j] = (__bf16)w1[j];
      }
      const int kk = half * 32 + s * 8;
      *(bf16x8*)&As[swz(r, kk)] = za;
      *(bf16x8*)&Bs[swz(r, kk)] = zw;
    }
    __syncthreads();
#pragma unroll
    for (int kk = 0; kk < 2; ++kk) {
      bf16x8 af[4], bfr[4];
#pragma unroll
      for (int i = 0; i < 4; ++i) {
        af[i]  = *(const bf16x8*)&As[swz(wm * 64 + i * 16 + (lane & 15), kk * 32 + (lane >> 4) * 8)];
        bfr[i] = *(const bf16x8*)&Bs[swz(wn * 64 + i * 16 + (lane & 15), kk * 32 + (lane >> 4) * 8)];
      }
#pragma unroll
      for (int mi = 0; mi < 4; ++mi)
#pragma unroll
        for (int ni = 0; ni < 4; ++ni)
          acc[mi][ni] = __builtin_amdgcn_mfma_f32_16x16x32_bf16(af[mi], bfr[ni], acc[mi][ni], 0, 0, 0);
    }
    __syncthreads();
  }

  const int rowbase = mt * 128 + wm * 64;
  const int colbase = nt * 128 + wn * 64;
#pragma unroll
  for (int ni = 0; ni < 4; ++ni) {
    const int col = colbase + ni * 16 + (lane & 15);
    const float bb = bias[col];
#pragma unroll
    for (int mi = 0; mi < 4; ++mi) {
      const int row = rowbase + mi * 16 + (lane >> 4) * 4;
#pragma unroll
      for (int rg = 0; rg < 4; ++rg)
        C[(size_t)(row + rg) * 640 + col] = acc[mi][ni][rg] + bb;
    }
  }
}

// ---------------------------------------------------------------------------
// prep: blocks 0..39 enc-proj, 40..49 pred-proj, 50..369 out_w conversion.
// out_w fp32 [1024][640] -> bf16 blocked [nb(4)][kb(10)][16384], pre-swizzled.
// ---------------------------------------------------------------------------
__global__ __launch_bounds__(256) void prep_kernel(
    const float* __restrict__ enc,  const float* __restrict__ enc_w,  const float* __restrict__ enc_b,
    const float* __restrict__ pred, const float* __restrict__ pred_w, const float* __restrict__ pred_b,
    const float* __restrict__ out_w,
    float* __restrict__ E, float* __restrict__ P, __bf16* __restrict__ Wb)
{
  __shared__ __align__(16) __bf16 As[128 * 64];
  __shared__ __align__(16) __bf16 Bs[128 * 64];
  const int bid = blockIdx.x;
  if (bid < 40) {
    proj_tile(enc, enc_w, enc_b, E, bid / 5, bid % 5, As, Bs);
  } else if (bid < 50) {
    proj_tile(pred, pred_w, pred_b, P, (bid - 40) / 5, (bid - 40) % 5, As, Bs);
  } else {
    const int gid = (bid - 50) * 256 + threadIdx.x;  // 81920 total (1024*80)
    const int v  = gid / 80;
    const int j8 = gid % 80;
    f32x4 w0 = *(const f32x4*)(out_w + (size_t)v * 640 + j8 * 8);
    f32x4 w1 = *(const f32x4*)(out_w + (size_t)v * 640 + j8 * 8 + 4);
    bf16x8 z;
#pragma unroll
    for (int j = 0; j < 4; ++j) { z[j] = (__bf16)w0[j]; z[4 + j] = (__bf16)w1[j]; }
    const int nb = v >> 8, rr = v & 255;
    const int kb = j8 >> 3, kk = (j8 & 7) * 8;
    *(bf16x8*)(Wb + ((size_t)(nb * 10 + kb) << 14) + swz(rr, kk)) = z;
  }
}

// ---------------------------------------------------------------------------
// main: fused tanh(E+P) x Wb GEMM, 256x256 tile, 4-phase/K-tile schedule
// (m201-style: raw s_barrier, counted waits, setprio, dbuf LDS 128KB).
// 512 thr = 8 waves (2M x 4N), wave-tile 128x64, BK=64, 10 K-tiles.
// B-frags held in regs across phases (each LDS frag read once per K-tile).
// A[t+1] produced (tanh) in phases 2-3; B[t+1] via global_load_lds in phase 0.
// ---------------------------------------------------------------------------
__global__ __launch_bounds__(512, 2) void joiner_main(
    const float* __restrict__ E, const float* __restrict__ P,
    const __bf16* __restrict__ Wb, const float* __restrict__ outb,
    float* __restrict__ out)
{
  __shared__ __align__(16) __bf16 As[2][16384];   // 64 KB
  __shared__ __align__(16) __bf16 Bs[2][16384];   // 64 KB
  const int tid = threadIdx.x;
  const int nt = blockIdx.x & 3;
  const int mt = blockIdx.x >> 2;
  const int row0 = mt << 8;            // 256 rows per tile
  const int b  = row0 >> 14;
  const int t0 = (row0 >> 6) & 255;    // 4 t-values per tile
  const int lane = tid & 63, wv = tid >> 6;
  const int wm = wv >> 2, wn = wv & 3; // 2 x 4 wave grid, wave-tile 128x64

  // A-production mapping: thread -> row ar, k-half h (32 k each)
  const int ar = tid & 255;
  const int h  = tid >> 8;
  const float* ep = E + (size_t)((b << 8) + t0 + (ar >> 6)) * 640 + h * 32;
  const float* pp = P + (size_t)((b << 6) + (ar & 63)) * 640 + h * 32;
  const __bf16* wsrc = Wb + ((size_t)(nt * 10) << 14);

  const int arow = wm * 128 + (lane & 15);
  const int brow = wn * 64  + (lane & 15);
  const int kcol = (lane >> 4) * 8;

  f32x4 acc[8][4] = {};
  bf16x8 bfr[4][2];
  f32x4 ec[4], pc[4];

  // ---------------- prologue: tile 0 into buffers[0] ----------------
#pragma unroll
  for (int c = 0; c < 4; ++c)
    gload_lds16(wsrc + c * 4096 + wv * 512 + lane * 8, &Bs[0][c * 4096 + wv * 512]);
#pragma unroll
  for (int c = 0; c < 2; ++c) {
#pragma unroll
    for (int i = 0; i < 4; ++i) {
      ec[i] = *(const f32x4*)(ep + c * 16 + i * 4);
      pc[i] = *(const f32x4*)(pp + c * 16 + i * 4);
    }
    bf16x8 z0, z1;
#pragma unroll
    for (int j = 0; j < 4; ++j) {
      z0[j]     = (__bf16)fast_tanh(ec[0][j] + pc[0][j]);
      z0[4 + j] = (__bf16)fast_tanh(ec[1][j] + pc[1][j]);
      z1[j]     = (__bf16)fast_tanh(ec[2][j] + pc[2][j]);
      z1[4 + j] = (__bf16)fast_tanh(ec[3][j] + pc[3][j]);
    }
    *(bf16x8*)&As[0][swz(ar, h * 32 + c * 16)]     = z0;
    *(bf16x8*)&As[0][swz(ar, h * 32 + c * 16 + 8)] = z1;
  }
  asm volatile("s_waitcnt vmcnt(0) lgkmcnt(0)" ::: "memory");
  __builtin_amdgcn_s_barrier();

  // ---------------- main loop: compute tile kt, stage kt+1 ----------------
  for (int kt = 0; kt < 9; ++kt) {
    const int cur = kt & 1;
    const __bf16* Asc = As[cur];
    const __bf16* Bsc = Bs[cur];
    __bf16* Asn = As[cur ^ 1];
    __bf16* Bsn = Bs[cur ^ 1];
    const int knext = (kt + 1) << 6;
    bf16x8 af[2][2];

    // ===== phase 0: stage B[t+1], read all B-frags + A m0,m1; MFMA m0,m1 =====
#pragma unroll
    for (int c = 0; c < 4; ++c)
      gload_lds16(wsrc + ((size_t)(kt + 1) << 14) + c * 4096 + wv * 512 + lane * 8,
                  &Bsn[c * 4096 + wv * 512]);
#pragma unroll
    for (int ni = 0; ni < 4; ++ni)
#pragma unroll
      for (int kk = 0; kk < 2; ++kk)
        bfr[ni][kk] = *(const bf16x8*)&Bsc[swz(brow + ni * 16, kcol + kk * 32)];
#pragma unroll
    for (int lm = 0; lm < 2; ++lm)
#pragma unroll
      for (int kk = 0; kk < 2; ++kk)
        af[lm][kk] = *(const bf16x8*)&Asc[swz(arow + lm * 16, kcol + kk * 32)];
    __builtin_amdgcn_s_barrier();
    asm volatile("s_waitcnt lgkmcnt(0)" ::: "memory");
    __builtin_amdgcn_sched_barrier(0);
    __builtin_amdgcn_s_setprio(1);
#pragma unroll
    for (int kk = 0; kk < 2; ++kk)
#pragma unroll
      for (int lm = 0; lm < 2; ++lm)
#pragma unroll
        for (int ni = 0; ni < 4; ++ni)
          acc[lm][ni] = __builtin_amdgcn_mfma_f32_16x16x32_bf16(af[lm][kk], bfr[ni][kk], acc[lm][ni], 0, 0, 0);
    __builtin_amdgcn_s_setprio(0);
    __builtin_amdgcn_s_barrier();

    // ===== phase 1: issue E/P chunk0 (tile t+1); A m2,m3; MFMA =====
#pragma unroll
    for (int i = 0; i < 4; ++i) {
      ec[i] = *(const f32x4*)(ep + knext + i * 4);
      pc[i] = *(const f32x4*)(pp + knext + i * 4);
    }
#pragma unroll
    for (int lm = 0; lm < 2; ++lm)
#pragma unroll
      for (int kk = 0; kk < 2; ++kk)
        af[lm][kk] = *(const bf16x8*)&Asc[swz(arow + (2 + lm) * 16, kcol + kk * 32)];
    __builtin_amdgcn_s_barrier();
    asm volatile("s_waitcnt lgkmcnt(0)" ::: "memory");
    __builtin_amdgcn_sched_barrier(0);
    __builtin_amdgcn_s_setprio(1);
#pragma unroll
    for (int kk = 0; kk < 2; ++kk)
#pragma unroll
      for (int lm = 0; lm < 2; ++lm)
#pragma unroll
        for (int ni = 0; ni < 4; ++ni)
          acc[2 + lm][ni] = __builtin_amdgcn_mfma_f32_16x16x32_bf16(af[lm][kk], bfr[ni][kk], acc[2 + lm][ni], 0, 0, 0);
    __builtin_amdgcn_s_setprio(0);
    __builtin_amdgcn_s_barrier();

    // ===== phase 2: A m4,m5; tanh chunk0 -> Asn; issue chunk1; MFMA =====
#pragma unroll
    for (int lm = 0; lm < 2; ++lm)
#pragma unroll
      for (int kk = 0; kk < 2; ++kk)
        af[lm][kk] = *(const bf16x8*)&Asc[swz(arow + (4 + lm) * 16, kcol + kk * 32)];
    {
      bf16x8 z0, z1;
#pragma unroll
      for (int j = 0; j < 4; ++j) {
        z0[j]     = (__bf16)fast_tanh(ec[0][j] + pc[0][j]);
        z0[4 + j] = (__bf16)fast_tanh(ec[1][j] + pc[1][j]);
        z1[j]     = (__bf16)fast_tanh(ec[2][j] + pc[2][j]);
        z1[4 + j] = (__bf16)fast_tanh(ec[3][j] + pc[3][j]);
      }
      *(bf16x8*)&Asn[swz(ar, h * 32)]     = z0;
      *(bf16x8*)&Asn[swz(ar, h * 32 + 8)] = z1;
    }
#pragma unroll
    for (int i = 0; i < 4; ++i) {
      ec[i] = *(const f32x4*)(ep + knext + 16 + i * 4);
      pc[i] = *(const f32x4*)(pp + knext + 16 + i * 4);
    }
    asm volatile("s_waitcnt lgkmcnt(0)" ::: "memory");  // publish ds_writes pre-barrier
    __builtin_amdgcn_s_barrier();
    __builtin_amdgcn_sched_barrier(0);
    __builtin_amdgcn_s_setprio(1);
#pragma unroll
    for (int kk = 0; kk < 2; ++kk)
#pragma unroll
      for (int lm = 0; lm < 2; ++lm)
#pragma unroll
        for (int ni = 0; ni < 4; ++ni)
          acc[4 + lm][ni] = __builtin_amdgcn_mfma_f32_16x16x32_bf16(af[lm][kk], bfr[ni][kk], acc[4 + lm][ni], 0, 0, 0);
    __builtin_amdgcn_s_setprio(0);
    __builtin_amdgcn_s_barrier();

    // ===== phase 3: A m6,m7; tanh chunk1 -> Asn; drain vm; MFMA; tile barrier =====
#pragma unroll
    for (int lm = 0; lm < 2; ++lm)
#pragma unroll
      for (int kk = 0; kk < 2; ++kk)
        af[lm][kk] = *(const bf16x8*)&Asc[swz(arow + (6 + lm) * 16, kcol + kk * 32)];
    {
      bf16x8 z0, z1;
#pragma unroll
      for (int j = 0; j < 4; ++j) {
        z0[j]     = (__bf16)fast_tanh(ec[0][j] + pc[0][j]);
        z0[4 + j] = (__bf16)fast_tanh(ec[1][j] + pc[1][j]);
        z1[j]     = (__bf16)fast_tanh(ec[2][j] + pc[2][j]);
        z1[4 + j] = (__bf16)fast_tanh(ec[3][j] + pc[3][j]);
      }
      *(bf16x8*)&Asn[swz(ar, h * 32 + 16)] = z0;
      *(bf16x8*)&Asn[swz(ar, h * 32 + 24)] = z1;
    }
    asm volatile("s_waitcnt vmcnt(0) lgkmcnt(0)" ::: "memory");  // B[t+1] lds + writes done
    __builtin_amdgcn_s_barrier();
    __builtin_amdgcn_sched_barrier(0);
    __builtin_amdgcn_s_setprio(1);
#pragma unroll
    for (int kk = 0; kk < 2; ++kk)
#pragma unroll
      for (int lm = 0; lm < 2; ++lm)
#pragma unroll
        for (int ni = 0; ni < 4; ++ni)
          acc[6 + lm][ni] = __builtin_amdgcn_mfma_f32_16x16x32_bf16(af[lm][kk], bfr[ni][kk], acc[6 + lm][ni], 0, 0, 0);
    __builtin_amdgcn_s_setprio(0);
    __builtin_amdgcn_s_barrier();   // tile boundary
  }

  // ---------------- last tile (kt=9, buffers[1]), no staging ----------------
  {
    const __bf16* Asc = As[1];
    const __bf16* Bsc = Bs[1];
    bf16x8 af[2][2];
#pragma unroll
    for (int ni = 0; ni < 4; ++ni)
#pragma unroll
      for (int kk = 0; kk < 2; ++kk)
        bfr[ni][kk] = *(const bf16x8*)&Bsc[swz(brow + ni * 16, kcol + kk * 32)];
#pragma unroll
    for (int p = 0; p < 4; ++p) {
#pragma unroll
      for (int lm = 0; lm < 2; ++lm)
#pragma unroll
        for (int kk = 0; kk < 2; ++kk)
          af[lm][kk] = *(const bf16x8*)&Asc[swz(arow + (2 * p + lm) * 16, kcol + kk * 32)];
#pragma unroll
      for (int kk = 0; kk < 2; ++kk)
#pragma unroll
        for (int lm = 0; lm < 2; ++lm)
#pragma unroll
          for (int ni = 0; ni < 4; ++ni)
            acc[2 * p + lm][ni] = __builtin_amdgcn_mfma_f32_16x16x32_bf16(af[lm][kk], bfr[ni][kk], acc[2 * p + lm][ni], 0, 0, 0);
    }
  }

  // ---------------- epilogue: bias + store ----------------
  const int rowbase = row0 + wm * 128;
  const int colbase = (nt << 8) + wn * 64;
#pragma unroll
  for (int ni = 0; ni < 4; ++ni) {
    const int col = colbase + ni * 16 + (lane & 15);
    const float bb = outb[col];
#pragma unroll
    for (int mi = 0; mi < 8; ++mi) {
      const int row = rowbase + mi * 16 + (lane >> 4) * 4;
#pragma unroll
      for (int rg = 0; rg < 4; ++rg)
        out[(size_t)(row + rg) * 1024 + col] = acc[mi][ni][rg] + bb;
    }
  }
}

extern "C" void kernel_launch(void* const* d_in, const int* in_sizes, int n_in,
                              void* d_out, int out_size, void* d_ws, size_t ws_size,
                              hipStream_t stream) {
  const float* enc    = (const float*)d_in[0];
  const float* pred   = (const float*)d_in[1];
  const float* enc_w  = (const float*)d_in[2];
  const float* enc_b  = (const float*)d_in[3];
  const float* pred_w = (const float*)d_in[4];
  const float* pred_b = (const float*)d_in[5];
  const float* out_w  = (const float*)d_in[6];
  const float* out_b  = (const float*)d_in[7];
  float* out = (float*)d_out;

  char* ws = (char*)d_ws;
  float*  E  = (float*)(ws);                  // 1024*640 f32
  float*  P  = (float*)(ws + 2621440);        //  256*640 f32
  __bf16* Wb = (__bf16*)(ws + 3276800);       // 4*10*16384 bf16, pre-swizzled

  prep_kernel<<<dim3(370), dim3(256), 0, stream>>>(
      enc, enc_w, enc_b, pred, pred_w, pred_b, out_w, E, P, Wb);
  joiner_main<<<dim3(1024), dim3(512), 0, stream>>>(E, P, Wb, out_b, out);
}

// Round 5
// 172.844 us; speedup vs baseline: 1.5664x; 1.3569x over previous
//
#include <hip/hip_runtime.h>
#include <cstdint>
#include <cstddef>

// RNNT joiner: logits[b,t,u,v] = sum_j tanh(E[b,t,j]+P[b,u,j]) * out_w[v,j] + out_b[v]
// B=4 T=256 U=64 D=512 J=640 V=1024.  M = 65536 rows (b,t,u), N=1024, K=640.
//
// ws layout (bf16 E/P this round):
//   E  : bf16 [1024][640]             @ 0         (1,310,720 B)
//   P  : bf16 [ 256][640]             @ 1,310,720 (  327,680 B)
//   Wb : bf16 blocked [4][10][16384]  @ 1,638,400 (1,310,720 B)  pre-swizzled 256x64 blocks

typedef __attribute__((ext_vector_type(8))) __bf16 bf16x8;
typedef __attribute__((ext_vector_type(4))) float f32x4;

// XOR swizzle within a [row][64] bf16 tile (row stride 128B).
__device__ __forceinline__ int swz(int row, int kElem) {
  return (row << 6) + (kElem ^ ((row & 7) << 3));
}

__device__ __forceinline__ float fast_tanh(float x) {
  float e = __builtin_amdgcn_exp2f(x * 2.88539008177793f);  // e^(2x)
  return 1.0f - 2.0f * __builtin_amdgcn_rcpf(e + 1.0f);
}

__device__ __forceinline__ void gload_lds16(const void* g, void* l) {
  __builtin_amdgcn_global_load_lds(
      (const __attribute__((address_space(1))) void*)g,
      (__attribute__((address_space(3))) void*)l, 16, 0, 0);
}

// ---------------------------------------------------------------------------
// proj tile: C[mt*128..][nt*128..] = A[128][512] . W[128][512]^T + bias  (bf16 out)
// ---------------------------------------------------------------------------
__device__ void proj_tile(const float* __restrict__ A, const float* __restrict__ W,
                          const float* __restrict__ bias, __bf16* __restrict__ C,
                          int mt, int nt, __bf16* As, __bf16* Bs)
{
  const int tid  = threadIdx.x;
  const int r = tid & 127, half = tid >> 7;
  const int lane = tid & 63, wv = tid >> 6;
  const int wm = wv >> 1, wn = wv & 1;

  const float* arow = A + (size_t)(mt * 128 + r) * 512 + half * 32;
  const float* wrow = W + (size_t)(nt * 128 + r) * 512 + half * 32;

  f32x4 acc[4][4] = {};

  for (int k0 = 0; k0 < 512; k0 += 64) {
#pragma unroll
    for (int s = 0; s < 4; ++s) {
      f32x4 a0 = *(const f32x4*)(arow + k0 + s * 8);
      f32x4 a1 = *(const f32x4*)(arow + k0 + s * 8 + 4);
      f32x4 w0 = *(const f32x4*)(wrow + k0 + s * 8);
      f32x4 w1 = *(const f32x4*)(wrow + k0 + s * 8 + 4);
      bf16x8 za, zw;
#pragma unroll
      for (int j = 0; j < 4; ++j) {
        za[j] = (__bf16)a0[j]; za[4 + j] = (__bf16)a1[j];
        zw[j] = (__bf16)w0[j]; zw[4 + j] = (__bf16)w1[j];
      }
      const int kk = half * 32 + s * 8;
      *(bf16x8*)&As[swz(r, kk)] = za;
      *(bf16x8*)&Bs[swz(r, kk)] = zw;
    }
    __syncthreads();
#pragma unroll
    for (int kk = 0; kk < 2; ++kk) {
      bf16x8 af[4], bfr[4];
#pragma unroll
      for (int i = 0; i < 4; ++i) {
        af[i]  = *(const bf16x8*)&As[swz(wm * 64 + i * 16 + (lane & 15), kk * 32 + (lane >> 4) * 8)];
        bfr[i] = *(const bf16x8*)&Bs[swz(wn * 64 + i * 16 + (lane & 15), kk * 32 + (lane >> 4) * 8)];
      }
#pragma unroll
      for (int mi = 0; mi < 4; ++mi)
#pragma unroll
        for (int ni = 0; ni < 4; ++ni)
          acc[mi][ni] = __builtin_amdgcn_mfma_f32_16x16x32_bf16(af[mi], bfr[ni], acc[mi][ni], 0, 0, 0);
    }
    __syncthreads();
  }

  const int rowbase = mt * 128 + wm * 64;
  const int colbase = nt * 128 + wn * 64;
#pragma unroll
  for (int ni = 0; ni < 4; ++ni) {
    const int col = colbase + ni * 16 + (lane & 15);
    const float bb = bias[col];
#pragma unroll
    for (int mi = 0; mi < 4; ++mi) {
      const int row = rowbase + mi * 16 + (lane >> 4) * 4;
#pragma unroll
      for (int rg = 0; rg < 4; ++rg)
        C[(size_t)(row + rg) * 640 + col] = (__bf16)(acc[mi][ni][rg] + bb);
    }
  }
}

// ---------------------------------------------------------------------------
// prep: blocks 0..39 enc-proj, 40..49 pred-proj, 50..369 out_w conversion.
// ---------------------------------------------------------------------------
__global__ __launch_bounds__(256) void prep_kernel(
    const float* __restrict__ enc,  const float* __restrict__ enc_w,  const float* __restrict__ enc_b,
    const float* __restrict__ pred, const float* __restrict__ pred_w, const float* __restrict__ pred_b,
    const float* __restrict__ out_w,
    __bf16* __restrict__ E, __bf16* __restrict__ P, __bf16* __restrict__ Wb)
{
  __shared__ __align__(16) __bf16 As[128 * 64];
  __shared__ __align__(16) __bf16 Bs[128 * 64];
  const int bid = blockIdx.x;
  if (bid < 40) {
    proj_tile(enc, enc_w, enc_b, E, bid / 5, bid % 5, As, Bs);
  } else if (bid < 50) {
    proj_tile(pred, pred_w, pred_b, P, (bid - 40) / 5, (bid - 40) % 5, As, Bs);
  } else {
    const int gid = (bid - 50) * 256 + threadIdx.x;  // 81920 total (1024*80)
    const int v  = gid / 80;
    const int j8 = gid % 80;
    f32x4 w0 = *(const f32x4*)(out_w + (size_t)v * 640 + j8 * 8);
    f32x4 w1 = *(const f32x4*)(out_w + (size_t)v * 640 + j8 * 8 + 4);
    bf16x8 z;
#pragma unroll
    for (int j = 0; j < 4; ++j) { z[j] = (__bf16)w0[j]; z[4 + j] = (__bf16)w1[j]; }
    const int nb = v >> 8, rr = v & 255;
    const int kb = j8 >> 3, kk = (j8 & 7) * 8;
    *(bf16x8*)(Wb + ((size_t)(nb * 10 + kb) << 14) + swz(rr, kk)) = z;
  }
}

// ---------------------------------------------------------------------------
// main: fused tanh(E+P) x Wb GEMM.  Tile 128(M) x 256(N), BK=64, 512 thr =
// 8 waves (2M x 4N), wave-tile 64x64.  B double-buffered (2x32KB), A single
// (16KB) -> 80KB LDS -> 2 blocks/CU.  Per K-tile:
//   stage B[t+1] (gload_lds, issued FIRST) ; load E/P[t+1] -> regs (issued
//   after B so the tanh's implicit vmcnt use-wait also drains B[t+1]) ;
//   MFMA on tile t (setprio) ; barrier ; tanh -> As ; lgkm(0) ; barrier.
// No in-loop vmcnt(0): loads stay in flight across the MFMA phase.
// ---------------------------------------------------------------------------
__global__ __launch_bounds__(512, 4) void joiner_main(
    const __bf16* __restrict__ E, const __bf16* __restrict__ P,
    const __bf16* __restrict__ Wb, const float* __restrict__ outb,
    float* __restrict__ out)
{
  __shared__ __align__(16) __bf16 As[8192];        // 128x64, 16 KB
  __shared__ __align__(16) __bf16 Bs[2][16384];    // 2x 256x64, 64 KB
  const int tid = threadIdx.x;
  const int nt = blockIdx.x & 3;
  const int mt = blockIdx.x >> 2;
  const int row0 = mt << 7;
  const int b  = row0 >> 14;
  const int t0 = (row0 >> 6) & 255;
  const int ar = tid & 127, h = tid >> 7;          // A-prod: row ar, k-base h*16
  const int lane = tid & 63, wv = tid >> 6;
  const int wm = wv >> 2, wn = wv & 3;             // 2 x 4 wave grid

  const __bf16* ep = E + (size_t)((b << 8) + t0 + (ar >> 6)) * 640 + h * 16;
  const __bf16* pp = P + (size_t)((b << 6) + (ar & 63)) * 640 + h * 16;
  const __bf16* wsrc = Wb + ((size_t)(nt * 10) << 14);

  f32x4 acc[4][4] = {};
  bf16x8 eA[2], pA[2];

  auto stageB = [&](int kt, __bf16* dst) {
#pragma unroll
    for (int c = 0; c < 4; ++c)
      gload_lds16(wsrc + ((size_t)kt << 14) + c * 4096 + wv * 512 + lane * 8,
                  dst + c * 4096 + wv * 512);
  };
  auto loadEP = [&](int k0) {
#pragma unroll
    for (int c = 0; c < 2; ++c) {
      eA[c] = *(const bf16x8*)(ep + k0 + c * 8);
      pA[c] = *(const bf16x8*)(pp + k0 + c * 8);
    }
  };
  auto writeA = [&]() {
#pragma unroll
    for (int c = 0; c < 2; ++c) {
      bf16x8 z;
#pragma unroll
      for (int j = 0; j < 8; ++j)
        z[j] = (__bf16)fast_tanh((float)eA[c][j] + (float)pA[c][j]);
      *(bf16x8*)&As[swz(ar, h * 16 + c * 8)] = z;
    }
  };
  auto compute = [&](const __bf16* Bsc) {
#pragma unroll
    for (int kk = 0; kk < 2; ++kk) {
      bf16x8 af[4], bfr[4];
#pragma unroll
      for (int i = 0; i < 4; ++i) {
        af[i]  = *(const bf16x8*)&As[swz(wm * 64 + i * 16 + (lane & 15), kk * 32 + (lane >> 4) * 8)];
        bfr[i] = *(const bf16x8*)&Bsc[swz(wn * 64 + i * 16 + (lane & 15), kk * 32 + (lane >> 4) * 8)];
      }
      asm volatile("s_waitcnt lgkmcnt(0)" ::: "memory");
      __builtin_amdgcn_sched_barrier(0);
      __builtin_amdgcn_s_setprio(1);
#pragma unroll
      for (int mi = 0; mi < 4; ++mi)
#pragma unroll
        for (int ni = 0; ni < 4; ++ni)
          acc[mi][ni] = __builtin_amdgcn_mfma_f32_16x16x32_bf16(af[mi], bfr[ni], acc[mi][ni], 0, 0, 0);
      __builtin_amdgcn_s_setprio(0);
    }
  };

  // ---- prologue: tile 0 ----
  stageB(0, Bs[0]);
  loadEP(0);
  writeA();                                         // EP use-wait drains B[0] too
  asm volatile("s_waitcnt vmcnt(0) lgkmcnt(0)" ::: "memory");
  __builtin_amdgcn_s_barrier();

  // ---- main loop: compute tile kt, stage kt+1 ----
  for (int kt = 0; kt < 9; ++kt) {
    const int cur = kt & 1;
    stageB(kt + 1, Bs[cur ^ 1]);     // issued FIRST (oldest in vm queue)
    loadEP((kt + 1) << 6);           // issued after B -> its wait drains B
    compute(Bs[cur]);
    __builtin_amdgcn_s_barrier();    // all waves done reading As
    __builtin_amdgcn_sched_barrier(0);
    writeA();                        // tanh; implicit vmcnt wait covers B[t+1]
    asm volatile("s_waitcnt lgkmcnt(0)" ::: "memory");  // publish ds_writes
    __builtin_amdgcn_s_barrier();
  }
  // ---- last tile (kt=9, Bs[1]) ----
  compute(Bs[1]);

  // ---- epilogue: bias + store ----
  const int rowbase = row0 + wm * 64;
  const int colbase = (nt << 8) + wn * 64;
#pragma unroll
  for (int ni = 0; ni < 4; ++ni) {
    const int col = colbase + ni * 16 + (lane & 15);
    const float bb = outb[col];
#pragma unroll
    for (int mi = 0; mi < 4; ++mi) {
      const int row = rowbase + mi * 16 + (lane >> 4) * 4;
#pragma unroll
      for (int rg = 0; rg < 4; ++rg)
        out[(size_t)(row + rg) * 1024 + col] = acc[mi][ni][rg] + bb;
    }
  }
}

extern "C" void kernel_launch(void* const* d_in, const int* in_sizes, int n_in,
                              void* d_out, int out_size, void* d_ws, size_t ws_size,
                              hipStream_t stream) {
  const float* enc    = (const float*)d_in[0];
  const float* pred   = (const float*)d_in[1];
  const float* enc_w  = (const float*)d_in[2];
  const float* enc_b  = (const float*)d_in[3];
  const float* pred_w = (const float*)d_in[4];
  const float* pred_b = (const float*)d_in[5];
  const float* out_w  = (const float*)d_in[6];
  const float* out_b  = (const float*)d_in[7];
  float* out = (float*)d_out;

  char* ws = (char*)d_ws;
  __bf16* E  = (__bf16*)(ws);                 // 1024*640 bf16
  __bf16* P  = (__bf16*)(ws + 1310720);       //  256*640 bf16
  __bf16* Wb = (__bf16*)(ws + 1638400);       // 4*10*16384 bf16, pre-swizzled

  prep_kernel<<<dim3(370), dim3(256), 0, stream>>>(
      enc, enc_w, enc_b, pred, pred_w, pred_b, out_w, E, P, Wb);
  joiner_main<<<dim3(2048), dim3(512), 0, stream>>>(E, P, Wb, out_b, out);
}

// Round 6
// 171.720 us; speedup vs baseline: 1.5767x; 1.0065x over previous
//
#include <hip/hip_runtime.h>
#include <cstdint>
#include <cstddef>

// RNNT joiner: logits[b,t,u,v] = sum_j tanh(E[b,t,j]+P[b,u,j]) * out_w[v,j] + out_b[v]
// B=4 T=256 U=64 D=512 J=640 V=1024.  M = 65536 rows (b,t,u), N=1024, K=640.
//
// ws layout:
//   E  : bf16 [1024][640]             @ 0          (1,310,720 B)
//   P  : bf16 [ 256][640]             @ 1,310,720  (  327,680 B)
//   Wb : bf16 blocked [8][10][8192]   @ 1,638,400  (1,310,720 B)  pre-swizzled 128x64 blocks
//   Z  : bf16 blocked [512][10][8192] @ 2,949,120  (83,886,080 B) pre-swizzled 128x64 blocks
// Z-path total: 86,835,200 B.  If ws_size is smaller -> fused fallback (R5 path).

typedef __attribute__((ext_vector_type(8))) __bf16 bf16x8;
typedef __attribute__((ext_vector_type(4))) float f32x4;

// XOR swizzle within a [row][64] bf16 tile (row stride 128B).
__device__ __forceinline__ int swz(int row, int kElem) {
  return (row << 6) + (kElem ^ ((row & 7) << 3));
}

__device__ __forceinline__ float fast_tanh(float x) {
  float e = __builtin_amdgcn_exp2f(x * 2.88539008177793f);  // e^(2x)
  return 1.0f - 2.0f * __builtin_amdgcn_rcpf(e + 1.0f);
}

__device__ __forceinline__ void gload_lds16(const void* g, void* l) {
  __builtin_amdgcn_global_load_lds(
      (const __attribute__((address_space(1))) void*)g,
      (__attribute__((address_space(3))) void*)l, 16, 0, 0);
}

// ---------------------------------------------------------------------------
// proj tile: C[mt*128..][nt*128..] = A[128][512] . W[128][512]^T + bias  (bf16 out)
// ---------------------------------------------------------------------------
__device__ void proj_tile(const float* __restrict__ A, const float* __restrict__ W,
                          const float* __restrict__ bias, __bf16* __restrict__ C,
                          int mt, int nt, __bf16* As, __bf16* Bs)
{
  const int tid  = threadIdx.x;
  const int r = tid & 127, half = tid >> 7;
  const int lane = tid & 63, wv = tid >> 6;
  const int wm = wv >> 1, wn = wv & 1;

  const float* arow = A + (size_t)(mt * 128 + r) * 512 + half * 32;
  const float* wrow = W + (size_t)(nt * 128 + r) * 512 + half * 32;

  f32x4 acc[4][4] = {};

  for (int k0 = 0; k0 < 512; k0 += 64) {
#pragma unroll
    for (int s = 0; s < 4; ++s) {
      f32x4 a0 = *(const f32x4*)(arow + k0 + s * 8);
      f32x4 a1 = *(const f32x4*)(arow + k0 + s * 8 + 4);
      f32x4 w0 = *(const f32x4*)(wrow + k0 + s * 8);
      f32x4 w1 = *(const f32x4*)(wrow + k0 + s * 8 + 4);
      bf16x8 za, zw;
#pragma unroll
      for (int j = 0; j < 4; ++j) {
        za[j] = (__bf16)a0[j]; za[4 + j] = (__bf16)a1[j];
        zw[j] = (__bf16)w0[j]; zw[4 + j] = (__bf16)w1[j];
      }
      const int kk = half * 32 + s * 8;
      *(bf16x8*)&As[swz(r, kk)] = za;
      *(bf16x8*)&Bs[swz(r, kk)] = zw;
    }
    __syncthreads();
#pragma unroll
    for (int kk = 0; kk < 2; ++kk) {
      bf16x8 af[4], bfr[4];
#pragma unroll
      for (int i = 0; i < 4; ++i) {
        af[i]  = *(const bf16x8*)&As[swz(wm * 64 + i * 16 + (lane & 15), kk * 32 + (lane >> 4) * 8)];
        bfr[i] = *(const bf16x8*)&Bs[swz(wn * 64 + i * 16 + (lane & 15), kk * 32 + (lane >> 4) * 8)];
      }
#pragma unroll
      for (int mi = 0; mi < 4; ++mi)
#pragma unroll
        for (int ni = 0; ni < 4; ++ni)
          acc[mi][ni] = __builtin_amdgcn_mfma_f32_16x16x32_bf16(af[mi], bfr[ni], acc[mi][ni], 0, 0, 0);
    }
    __syncthreads();
  }

  const int rowbase = mt * 128 + wm * 64;
  const int colbase = nt * 128 + wn * 64;
#pragma unroll
  for (int ni = 0; ni < 4; ++ni) {
    const int col = colbase + ni * 16 + (lane & 15);
    const float bb = bias[col];
#pragma unroll
    for (int mi = 0; mi < 4; ++mi) {
      const int row = rowbase + mi * 16 + (lane >> 4) * 4;
#pragma unroll
      for (int rg = 0; rg < 4; ++rg)
        C[(size_t)(row + rg) * 640 + col] = (__bf16)(acc[mi][ni][rg] + bb);
    }
  }
}

// ---------------------------------------------------------------------------
// prep: blocks 0..39 enc-proj, 40..49 pred-proj, 50..369 out_w conversion.
// out_w fp32 [1024][640] -> bf16 blocked [nb(8)][kb(10)][8192], pre-swizzled.
// ---------------------------------------------------------------------------
__global__ __launch_bounds__(256) void prep_kernel(
    const float* __restrict__ enc,  const float* __restrict__ enc_w,  const float* __restrict__ enc_b,
    const float* __restrict__ pred, const float* __restrict__ pred_w, const float* __restrict__ pred_b,
    const float* __restrict__ out_w,
    __bf16* __restrict__ E, __bf16* __restrict__ P, __bf16* __restrict__ Wb)
{
  __shared__ __align__(16) __bf16 As[128 * 64];
  __shared__ __align__(16) __bf16 Bs[128 * 64];
  const int bid = blockIdx.x;
  if (bid < 40) {
    proj_tile(enc, enc_w, enc_b, E, bid / 5, bid % 5, As, Bs);
  } else if (bid < 50) {
    proj_tile(pred, pred_w, pred_b, P, (bid - 40) / 5, (bid - 40) % 5, As, Bs);
  } else {
    const int gid = (bid - 50) * 256 + threadIdx.x;  // 81920 total (1024*80)
    const int v  = gid / 80;
    const int j8 = gid % 80;
    f32x4 w0 = *(const f32x4*)(out_w + (size_t)v * 640 + j8 * 8);
    f32x4 w1 = *(const f32x4*)(out_w + (size_t)v * 640 + j8 * 8 + 4);
    bf16x8 z;
#pragma unroll
    for (int j = 0; j < 4; ++j) { z[j] = (__bf16)w0[j]; z[4 + j] = (__bf16)w1[j]; }
    const int nb = v >> 7, rr = v & 127;
    const int kb = j8 >> 3, kk = (j8 & 7) * 8;
    *(bf16x8*)(Wb + ((size_t)(nb * 10 + kb) << 13) + swz(rr, kk)) = z;
  }
}

// ---------------------------------------------------------------------------
// zprod: Z[mt][kt][8192] = tanh(E+P) for M-tile mt, K-tile kt, written in the
// pre-swizzled 128x64 block layout with LINEAR stores (o -> (r,k) inverted at
// the load side; XOR swizzle is an involution).  grid = 5120 (mt*10+kt).
// ---------------------------------------------------------------------------
__global__ __launch_bounds__(256) void zprod_kernel(
    const __bf16* __restrict__ E, const __bf16* __restrict__ P,
    __bf16* __restrict__ Z)
{
  const int bid = blockIdx.x;
  const int mt = bid / 10, kt = bid % 10;
  const int row0 = mt << 7;
  const int b  = row0 >> 14;
  const int t0 = (row0 >> 6) & 255;
  __bf16* zdst = Z + ((size_t)bid << 13);
  const int k0 = kt << 6;

#pragma unroll
  for (int c = 0; c < 4; ++c) {
    const int o = c * 2048 + threadIdx.x * 8;   // linear offset in block
    const int r = o >> 6;
    const int k = (o & 63) ^ ((r & 7) << 3);    // inverse of swz
    const __bf16* ep = E + (size_t)((b << 8) + t0 + (r >> 6)) * 640 + k0 + k;
    const __bf16* pp = P + (size_t)((b << 6) + (r & 63)) * 640 + k0 + k;
    bf16x8 e8 = *(const bf16x8*)ep;
    bf16x8 p8 = *(const bf16x8*)pp;
    bf16x8 z;
#pragma unroll
    for (int j = 0; j < 8; ++j)
      z[j] = (__bf16)fast_tanh((float)e8[j] + (float)p8[j]);
    *(bf16x8*)&zdst[o] = z;
  }
}

// ---------------------------------------------------------------------------
// main (Z-path): pure bf16 GEMM, m97 structure.  Tile 128x128, BK=64,
// 256 thr = 4 waves (2x2), wave-tile 64x64, both operands via global_load_lds
// from pre-swizzled blocks, single-buffered 2-barrier loop, 32KB LDS.
// Grid 4096 = 512 mt x 8 nt, bijective XCD swizzle (4096 % 8 == 0).
// ---------------------------------------------------------------------------
__global__ __launch_bounds__(256) void joiner_mainz(
    const __bf16* __restrict__ Z, const __bf16* __restrict__ Wb,
    const float* __restrict__ outb, float* __restrict__ out)
{
  __shared__ __align__(16) __bf16 As[8192];   // 16 KB
  __shared__ __align__(16) __bf16 Bs[8192];   // 16 KB
  const int wg = blockIdx.x;
  const int bid = (wg & 7) * 512 + (wg >> 3); // XCD-contiguous logical id
  const int mt = bid >> 3, nt = bid & 7;
  const int tid = threadIdx.x;
  const int lane = tid & 63, wv = tid >> 6;
  const int wm = wv >> 1, wn = wv & 1;

  const __bf16* zsrc = Z  + ((size_t)(mt * 10) << 13);
  const __bf16* wsrc = Wb + ((size_t)(nt * 10) << 13);

  f32x4 acc[4][4] = {};

  for (int kt = 0; kt < 10; ++kt) {
    const size_t kb = (size_t)kt << 13;
#pragma unroll
    for (int c = 0; c < 4; ++c) {
      const int off = c * 2048 + wv * 512;
      gload_lds16(zsrc + kb + off + lane * 8, &As[off]);
      gload_lds16(wsrc + kb + off + lane * 8, &Bs[off]);
    }
    __syncthreads();
#pragma unroll
    for (int kk = 0; kk < 2; ++kk) {
      bf16x8 af[4], bfr[4];
#pragma unroll
      for (int i = 0; i < 4; ++i) {
        af[i]  = *(const bf16x8*)&As[swz(wm * 64 + i * 16 + (lane & 15), kk * 32 + (lane >> 4) * 8)];
        bfr[i] = *(const bf16x8*)&Bs[swz(wn * 64 + i * 16 + (lane & 15), kk * 32 + (lane >> 4) * 8)];
      }
#pragma unroll
      for (int mi = 0; mi < 4; ++mi)
#pragma unroll
        for (int ni = 0; ni < 4; ++ni)
          acc[mi][ni] = __builtin_amdgcn_mfma_f32_16x16x32_bf16(af[mi], bfr[ni], acc[mi][ni], 0, 0, 0);
    }
    __syncthreads();
  }

  const int rowbase = (mt << 7) + wm * 64;
  const int colbase = (nt << 7) + wn * 64;
#pragma unroll
  for (int ni = 0; ni < 4; ++ni) {
    const int col = colbase + ni * 16 + (lane & 15);
    const float bb = outb[col];
#pragma unroll
    for (int mi = 0; mi < 4; ++mi) {
      const int row = rowbase + mi * 16 + (lane >> 4) * 4;
#pragma unroll
      for (int rg = 0; rg < 4; ++rg)
        out[(size_t)(row + rg) * 1024 + col] = acc[mi][ni][rg] + bb;
    }
  }
}

// ---------------------------------------------------------------------------
// Fallback (small ws): R5 fused kernel.  Tile 128x256, BK=64, 512 thr,
// wave-tile 64x64, B double-buffered via gload_lds, A produced by tanh.
// Reads the 128-col-blocked Wb (two blocks per 256-col tile).
// ---------------------------------------------------------------------------
__global__ __launch_bounds__(512, 4) void joiner_fused(
    const __bf16* __restrict__ E, const __bf16* __restrict__ P,
    const __bf16* __restrict__ Wb, const float* __restrict__ outb,
    float* __restrict__ out)
{
  __shared__ __align__(16) __bf16 As[8192];        // 128x64, 16 KB
  __shared__ __align__(16) __bf16 Bs[2][16384];    // 2x 256x64, 64 KB
  const int tid = threadIdx.x;
  const int nt = blockIdx.x & 3;
  const int mt = blockIdx.x >> 2;
  const int row0 = mt << 7;
  const int b  = row0 >> 14;
  const int t0 = (row0 >> 6) & 255;
  const int ar = tid & 127, h = tid >> 7;
  const int lane = tid & 63, wv = tid >> 6;
  const int wm = wv >> 2, wn = wv & 3;

  const __bf16* ep = E + (size_t)((b << 8) + t0 + (ar >> 6)) * 640 + h * 16;
  const __bf16* pp = P + (size_t)((b << 6) + (ar & 63)) * 640 + h * 16;

  f32x4 acc[4][4] = {};
  bf16x8 eA[2], pA[2];

  auto stageB = [&](int kt, __bf16* dst) {
#pragma unroll
    for (int c = 0; c < 4; ++c) {
      const int blk = nt * 2 + (c >> 1);
      const int off = (c & 1) * 4096 + wv * 512;
      gload_lds16(Wb + ((size_t)(blk * 10 + kt) << 13) + off + lane * 8,
                  dst + c * 2048 * 2 - (c >> 1) * 8192 + ((c & 1) * 4096 + wv * 512) - ((c & 1) * 4096 + wv * 512) + (c * 4096 - (c >> 1) * 8192) * 0 + 0);
    }
  };
  // (rewritten below without the degenerate expression)
  (void)stageB;

  auto stageB2 = [&](int kt, __bf16* dst) {
#pragma unroll
    for (int c = 0; c < 4; ++c) {
      const int blk = nt * 2 + (c >> 1);
      const int inoff = (c & 1) * 4096 + wv * 512;
      gload_lds16(Wb + ((size_t)(blk * 10 + kt) << 13) + inoff + lane * 8,
                  dst + (c >> 1) * 8192 + inoff);
    }
  };
  auto loadEP = [&](int k0) {
#pragma unroll
    for (int c = 0; c < 2; ++c) {
      eA[c] = *(const bf16x8*)(ep + k0 + c * 8);
      pA[c] = *(const bf16x8*)(pp + k0 + c * 8);
    }
  };
  auto writeA = [&]() {
#pragma unroll
    for (int c = 0; c < 2; ++c) {
      bf16x8 z;
#pragma unroll
      for (int j = 0; j < 8; ++j)
        z[j] = (__bf16)fast_tanh((float)eA[c][j] + (float)pA[c][j]);
      *(bf16x8*)&As[swz(ar, h * 16 + c * 8)] = z;
    }
  };
  auto compute = [&](const __bf16* Bsc) {
#pragma unroll
    for (int kk = 0; kk < 2; ++kk) {
      bf16x8 af[4], bfr[4];
#pragma unroll
      for (int i = 0; i < 4; ++i) {
        af[i]  = *(const bf16x8*)&As[swz(wm * 64 + i * 16 + (lane & 15), kk * 32 + (lane >> 4) * 8)];
        bfr[i] = *(const bf16x8*)&Bsc[swz(wn * 64 + i * 16 + (lane & 15), kk * 32 + (lane >> 4) * 8)];
      }
      asm volatile("s_waitcnt lgkmcnt(0)" ::: "memory");
      __builtin_amdgcn_sched_barrier(0);
      __builtin_amdgcn_s_setprio(1);
#pragma unroll
      for (int mi = 0; mi < 4; ++mi)
#pragma unroll
        for (int ni = 0; ni < 4; ++ni)
          acc[mi][ni] = __builtin_amdgcn_mfma_f32_16x16x32_bf16(af[mi], bfr[ni], acc[mi][ni], 0, 0, 0);
      __builtin_amdgcn_s_setprio(0);
    }
  };

  stageB2(0, Bs[0]);
  loadEP(0);
  writeA();
  asm volatile("s_waitcnt vmcnt(0) lgkmcnt(0)" ::: "memory");
  __builtin_amdgcn_s_barrier();

  for (int kt = 0; kt < 9; ++kt) {
    const int cur = kt & 1;
    stageB2(kt + 1, Bs[cur ^ 1]);
    loadEP((kt + 1) << 6);
    compute(Bs[cur]);
    __builtin_amdgcn_s_barrier();
    __builtin_amdgcn_sched_barrier(0);
    writeA();
    asm volatile("s_waitcnt lgkmcnt(0)" ::: "memory");
    __builtin_amdgcn_s_barrier();
  }
  compute(Bs[1]);

  const int rowbase = row0 + wm * 64;
  const int colbase = (nt << 8) + wn * 64;
#pragma unroll
  for (int ni = 0; ni < 4; ++ni) {
    const int col = colbase + ni * 16 + (lane & 15);
    const float bb = outb[col];
#pragma unroll
    for (int mi = 0; mi < 4; ++mi) {
      const int row = rowbase + mi * 16 + (lane >> 4) * 4;
#pragma unroll
      for (int rg = 0; rg < 4; ++rg)
        out[(size_t)(row + rg) * 1024 + col] = acc[mi][ni][rg] + bb;
    }
  }
}

extern "C" void kernel_launch(void* const* d_in, const int* in_sizes, int n_in,
                              void* d_out, int out_size, void* d_ws, size_t ws_size,
                              hipStream_t stream) {
  const float* enc    = (const float*)d_in[0];
  const float* pred   = (const float*)d_in[1];
  const float* enc_w  = (const float*)d_in[2];
  const float* enc_b  = (const float*)d_in[3];
  const float* pred_w = (const float*)d_in[4];
  const float* pred_b = (const float*)d_in[5];
  const float* out_w  = (const float*)d_in[6];
  const float* out_b  = (const float*)d_in[7];
  float* out = (float*)d_out;

  char* ws = (char*)d_ws;
  __bf16* E  = (__bf16*)(ws);                 // 1024*640 bf16
  __bf16* P  = (__bf16*)(ws + 1310720);       //  256*640 bf16
  __bf16* Wb = (__bf16*)(ws + 1638400);       // 8*10*8192 bf16, pre-swizzled
  __bf16* Z  = (__bf16*)(ws + 2949120);       // 512*10*8192 bf16, pre-swizzled

  prep_kernel<<<dim3(370), dim3(256), 0, stream>>>(
      enc, enc_w, enc_b, pred, pred_w, pred_b, out_w, E, P, Wb);

  if (ws_size >= (size_t)86835200) {
    zprod_kernel<<<dim3(5120), dim3(256), 0, stream>>>(E, P, Z);
    joiner_mainz<<<dim3(4096), dim3(256), 0, stream>>>(Z, Wb, out_b, out);
  } else {
    joiner_fused<<<dim3(2048), dim3(512), 0, stream>>>(E, P, Wb, out_b, out);
  }
}